// Round 2
// baseline (355.847 us; speedup 1.0000x reference)
//
#include <hip/hip_runtime.h>
#include <hip/hip_bf16.h>

typedef __attribute__((ext_vector_type(8))) short bf16x8;
typedef __attribute__((ext_vector_type(4))) float f32x4;
typedef __attribute__((ext_vector_type(4))) unsigned int u32x4;

#define DD 1024
#define KC 256
#define BM 64
#define NSTEP 32          // K-steps of 32
#define CLAMP_EPS 1e-8f

__device__ __forceinline__ unsigned short f2bf(float f) {
  unsigned int u = __float_as_uint(f);
  u += 0x7FFFu + ((u >> 16) & 1u);   // RNE
  return (unsigned short)(u >> 16);
}

__device__ __forceinline__ unsigned int pk2(float x, float y) {
  __hip_bfloat162 h = __float22bfloat162_rn(float2{x, y});
  return *reinterpret_cast<unsigned int*>(&h);
}

// 8 fp32 (two f32x4) -> packed bf16x8 via hw cvt_pk
__device__ __forceinline__ bf16x8 cvt8(f32x4 lo, f32x4 hi) {
  u32x4 w;
  w[0] = pk2(lo[0], lo[1]);
  w[1] = pk2(lo[2], lo[3]);
  w[2] = pk2(hi[0], hi[1]);
  w[3] = pk2(hi[2], hi[3]);
  return __builtin_bit_cast(bf16x8, w);
}

// Kernel 1: per-center inverse-norm + prenormalized bf16 copy into ws.
__global__ __launch_bounds__(64) void center_norm_kernel(
    const float* __restrict__ c, short* __restrict__ cn) {
  const int k = blockIdx.x;
  const int lane = threadIdx.x;
  const float* row = c + (size_t)k * DD + lane * 16;
  f32x4 v0 = *(const f32x4*)(row);
  f32x4 v1 = *(const f32x4*)(row + 4);
  f32x4 v2 = *(const f32x4*)(row + 8);
  f32x4 v3 = *(const f32x4*)(row + 12);
  float ss = 0.f;
  #pragma unroll
  for (int j = 0; j < 4; ++j)
    ss += v0[j]*v0[j] + v1[j]*v1[j] + v2[j]*v2[j] + v3[j]*v3[j];
  #pragma unroll
  for (int off = 32; off > 0; off >>= 1) ss += __shfl_xor(ss, off, 64);
  const float inv = 1.f / fmaxf(sqrtf(ss), CLAMP_EPS);
  bf16x8 lo, hi;
  #pragma unroll
  for (int j = 0; j < 4; ++j) {
    lo[j]     = (short)f2bf(v0[j] * inv);
    lo[j + 4] = (short)f2bf(v1[j] * inv);
    hi[j]     = (short)f2bf(v2[j] * inv);
    hi[j + 4] = (short)f2bf(v3[j] * inv);
  }
  short* o = cn + (size_t)k * DD + lane * 16;
  *(bf16x8*)o = lo;
  *(bf16x8*)(o + 8) = hi;
}

// Kernel 2: LDS-free, barrier-free fused cosine-sim GEMM.
// Block: 512 thr = 8 waves (wm 0..1 x wn 0..3); wave tile 32x64.
// A/B fragments loaded straight from global in MFMA lane layout.
// ssq accumulated lane-locally, reduced with 2 shfl_xor.
__global__ __launch_bounds__(512, 4) void cossim_gemm_kernel(
    const float* __restrict__ x, const short* __restrict__ cn,
    float* __restrict__ out) {
  const int t = threadIdx.x;
  const int lane = t & 63;
  const int wid = t >> 6;
  const int wm = wid >> 2;     // 0..1 -> 32-row slab
  const int wn = wid & 3;      // 0..3 -> 64-col slab
  const int row0 = blockIdx.x * BM;

  const int fr = lane & 15;
  const int kg = (lane >> 4) * 8;     // k sub-chunk within a 32-k step

  // A fragment base pointers (fp32), fm = 0,1
  const float* ap0 = x + (size_t)(row0 + wm * 32 + fr) * DD + kg;
  const float* ap1 = ap0 + 16 * DD;
  // B fragment base pointers (prenormalized bf16), fn = 0..3
  const short* bp0 = cn + (size_t)(wn * 64 + fr) * DD + kg;
  const short* bp1 = bp0 + 16 * DD;
  const short* bp2 = bp0 + 32 * DD;
  const short* bp3 = bp0 + 48 * DD;

  f32x4 aA[2][2], aB[2][2];   // [buf][half] raw fp32 A frags (fm=0 / fm=1)
  u32x4 bb[2][4];             // [buf][fn]   bf16 B frags
  f32x4 acc[2][4];
  #pragma unroll
  for (int i = 0; i < 2; ++i)
    #pragma unroll
    for (int j = 0; j < 4; ++j) acc[i][j] = (f32x4)(0.f);
  float ssq0 = 0.f, ssq1 = 0.f;

#define PREFETCH(B, S) do {                                        \
    const int _o = (S) * 32;                                       \
    aA[B][0] = *(const f32x4*)(ap0 + _o);                          \
    aA[B][1] = *(const f32x4*)(ap0 + _o + 4);                      \
    aB[B][0] = *(const f32x4*)(ap1 + _o);                          \
    aB[B][1] = *(const f32x4*)(ap1 + _o + 4);                      \
    bb[B][0] = *(const u32x4*)(bp0 + _o);                          \
    bb[B][1] = *(const u32x4*)(bp1 + _o);                          \
    bb[B][2] = *(const u32x4*)(bp2 + _o);                          \
    bb[B][3] = *(const u32x4*)(bp3 + _o);                          \
  } while (0)

  PREFETCH(0, 0);

  #pragma unroll
  for (int s = 0; s < NSTEP; ++s) {
    const int cur = s & 1;
    if (s + 1 < NSTEP) {
      const int nxt = cur ^ 1;
      PREFETCH(nxt, s + 1);
    }
    // fp32 sum-of-squares on raw A
    #pragma unroll
    for (int j = 0; j < 4; ++j) {
      ssq0 = fmaf(aA[cur][0][j], aA[cur][0][j], ssq0);
      ssq0 = fmaf(aA[cur][1][j], aA[cur][1][j], ssq0);
      ssq1 = fmaf(aB[cur][0][j], aB[cur][0][j], ssq1);
      ssq1 = fmaf(aB[cur][1][j], aB[cur][1][j], ssq1);
    }
    const bf16x8 af0 = cvt8(aA[cur][0], aA[cur][1]);
    const bf16x8 af1 = cvt8(aB[cur][0], aB[cur][1]);
    #pragma unroll
    for (int fn = 0; fn < 4; ++fn) {
      const bf16x8 bf = __builtin_bit_cast(bf16x8, bb[cur][fn]);
      acc[0][fn] = __builtin_amdgcn_mfma_f32_16x16x32_bf16(af0, bf, acc[0][fn], 0, 0, 0);
      acc[1][fn] = __builtin_amdgcn_mfma_f32_16x16x32_bf16(af1, bf, acc[1][fn], 0, 0, 0);
    }
  }
#undef PREFETCH

  // reduce ssq across the 4 k-lane-groups: lanes {l, l^16, l^32, l^48}
  ssq0 += __shfl_xor(ssq0, 16, 64);
  ssq0 += __shfl_xor(ssq0, 32, 64);
  ssq1 += __shfl_xor(ssq1, 16, 64);
  ssq1 += __shfl_xor(ssq1, 32, 64);
  const float inv0 = 1.f / fmaxf(sqrtf(ssq0), CLAMP_EPS);  // row wm*32 + fr
  const float inv1 = 1.f / fmaxf(sqrtf(ssq1), CLAMP_EPS);  // row wm*32 + 16 + fr

  // epilogue: C/D layout col=lane&15, row=(lane>>4)*4+reg
  #pragma unroll
  for (int fm = 0; fm < 2; ++fm) {
    const float invf = fm ? inv1 : inv0;
    #pragma unroll
    for (int r = 0; r < 4; ++r) {
      const int ri = (lane >> 4) * 4 + r;            // row within 16-row frag
      const float inv = __shfl(invf, ri, 64);        // ssq lives at lane&15==ri
      float* orow = out + (size_t)(row0 + wm * 32 + fm * 16 + ri) * KC
                    + wn * 64 + fr;
      #pragma unroll
      for (int fn = 0; fn < 4; ++fn)
        orow[fn * 16] = fmaf(acc[fm][fn][r] * inv, 0.5f, 0.5f);
    }
  }
}

extern "C" void kernel_launch(void* const* d_in, const int* in_sizes, int n_in,
                              void* d_out, int out_size, void* d_ws, size_t ws_size,
                              hipStream_t stream) {
  const float* x = (const float*)d_in[0];
  const float* c = (const float*)d_in[1];
  float* out = (float*)d_out;
  short* cn = (short*)d_ws;              // 256*1024 bf16 = 512 KB

  const int nrows = in_sizes[0] / DD;    // 32768
  center_norm_kernel<<<KC, 64, 0, stream>>>(c, cn);
  cossim_gemm_kernel<<<nrows / BM, 512, 0, stream>>>(x, cn, out);
}

// Round 3
// 37.444 us; speedup vs baseline: 9.5033x; 9.5033x over previous
//
#include <hip/hip_runtime.h>
#include <hip/hip_bf16.h>

typedef __attribute__((ext_vector_type(8))) short bf16x8;
typedef __attribute__((ext_vector_type(4))) float f32x4;
typedef __attribute__((ext_vector_type(4))) unsigned int u32x4;

#define DD 1024
#define KC 256
#define BM 64
#define BK 64
#define KSTEPS (DD / BK)      // 16
#define BUF_BYTES 40960       // As (8KB) + Bs (32KB) per buffer
#define CLAMP_EPS 1e-8f

__device__ __forceinline__ unsigned short f2bf(float f) {
  unsigned int u = __float_as_uint(f);
  u += 0x7FFFu + ((u >> 16) & 1u);   // RNE
  return (unsigned short)(u >> 16);
}

__device__ __forceinline__ unsigned int pk2(float x, float y) {
  __hip_bfloat162 h = __float22bfloat162_rn(float2{x, y});
  return *reinterpret_cast<unsigned int*>(&h);
}

__device__ __forceinline__ bf16x8 cvt8(f32x4 lo, f32x4 hi) {
  u32x4 w;
  w[0] = pk2(lo[0], lo[1]);
  w[1] = pk2(lo[2], lo[3]);
  w[2] = pk2(hi[0], hi[1]);
  w[3] = pk2(hi[2], hi[3]);
  return __builtin_bit_cast(bf16x8, w);
}

// async global->LDS, 16B per lane; LDS dest is wave-uniform base + lane*16
__device__ __forceinline__ void gload_lds16(const short* g, short* l) {
  __builtin_amdgcn_global_load_lds(
      (__attribute__((address_space(1))) void*)g,
      (__attribute__((address_space(3))) void*)l, 16, 0, 0);
}

// Kernel 1: per-center inverse-norm + prenormalized bf16 copy into ws.
__global__ __launch_bounds__(64) void center_norm_kernel(
    const float* __restrict__ c, short* __restrict__ cn) {
  const int k = blockIdx.x;
  const int lane = threadIdx.x;
  const float* row = c + (size_t)k * DD + lane * 16;
  f32x4 v0 = *(const f32x4*)(row);
  f32x4 v1 = *(const f32x4*)(row + 4);
  f32x4 v2 = *(const f32x4*)(row + 8);
  f32x4 v3 = *(const f32x4*)(row + 12);
  float ss = 0.f;
  #pragma unroll
  for (int j = 0; j < 4; ++j)
    ss += v0[j]*v0[j] + v1[j]*v1[j] + v2[j]*v2[j] + v3[j]*v3[j];
  #pragma unroll
  for (int off = 32; off > 0; off >>= 1) ss += __shfl_xor(ss, off, 64);
  const float inv = 1.f / fmaxf(sqrtf(ss), CLAMP_EPS);
  bf16x8 lo, hi;
  #pragma unroll
  for (int j = 0; j < 4; ++j) {
    lo[j]     = (short)f2bf(v0[j] * inv);
    lo[j + 4] = (short)f2bf(v1[j] * inv);
    hi[j]     = (short)f2bf(v2[j] * inv);
    hi[j + 4] = (short)f2bf(v3[j] * inv);
  }
  short* o = cn + (size_t)k * DD + lane * 16;
  *(bf16x8*)o = lo;
  *(bf16x8*)(o + 8) = hi;
}

// Kernel 2: fused cosine-sim GEMM, double-buffered LDS, 1 barrier per K-step.
// Per step: issue B gload_lds(next) + A cvt+ds_write(next, from regs) +
// A global->reg(next+1), THEN ds_read+MFMA(cur), THEN one barrier.
__global__ __launch_bounds__(512, 4) void cossim_gemm_kernel(
    const float* __restrict__ x, const short* __restrict__ cn,
    float* __restrict__ out) {
  __shared__ __align__(16) char lds_raw[2 * BUF_BYTES];   // 80 KB

  const int t = threadIdx.x;
  const int lane = t & 63;
  const int wid = t >> 6;
  const int wm = wid >> 2;     // 0..1
  const int wn = wid & 3;      // 0..3
  const int fr = lane & 15;
  const int row0 = blockIdx.x * BM;

  // ---- A staging geometry: thread owns (row ar, 8-float segment aseg)
  const int ar = t >> 3;
  const int aseg = t & 7;
  const float* aptr = x + (size_t)(row0 + ar) * DD + aseg * 8;
  const int sA = (ar * BK + aseg * 8) ^ ((ar & 7) << 3);   // swizzled, shorts

  // ---- B staging via gload_lds: 4 wave-instrs; source pre-swizzled so that
  // linear LDS dest == XOR-swizzled layout (rule #21)
  const short* bsrc0; const short* bsrc1; const short* bsrc2; const short* bsrc3;
  int bld0, bld1, bld2, bld3;
  {
    #define BGEO(i, PS, PL) {                       \
      const int g = (wid * 4 + (i)) * 64 + lane;    \
      const int n = g >> 3;                         \
      const int cp = (g & 7) ^ (n & 7);             \
      PS = cn + n * DD + cp * 8;                    \
      PL = (wid * 4 + (i)) * 512; }
    BGEO(0, bsrc0, bld0) BGEO(1, bsrc1, bld1)
    BGEO(2, bsrc2, bld2) BGEO(3, bsrc3, bld3)
    #undef BGEO
  }

  float ssq = 0.f;

  // ---- prologue: stage tile 0 into buffer 0, prefetch A tile 1 to regs
  f32x4 rA0 = *(const f32x4*)(aptr);
  f32x4 rA1 = *(const f32x4*)(aptr + 4);
  {
    short* bsb = (short*)(lds_raw + 8192);
    gload_lds16(bsrc0, bsb + bld0);
    gload_lds16(bsrc1, bsb + bld1);
    gload_lds16(bsrc2, bsb + bld2);
    gload_lds16(bsrc3, bsb + bld3);
  }
  #pragma unroll
  for (int j = 0; j < 4; ++j) {
    ssq = fmaf(rA0[j], rA0[j], ssq);
    ssq = fmaf(rA1[j], rA1[j], ssq);
  }
  *(bf16x8*)&((short*)lds_raw)[sA] = cvt8(rA0, rA1);
  rA0 = *(const f32x4*)(aptr + BK);
  rA1 = *(const f32x4*)(aptr + BK + 4);
  __syncthreads();

  f32x4 acc[2][4];
  #pragma unroll
  for (int i = 0; i < 2; ++i)
    #pragma unroll
    for (int j = 0; j < 4; ++j) acc[i][j] = (f32x4)(0.f);

  #pragma unroll
  for (int ks = 0; ks < KSTEPS; ++ks) {
    const int cb = ks & 1;
    const int nb = cb ^ 1;
    // ---- stage tile ks+1 into buffer nb (issued BEFORE compute)
    if (ks + 1 < KSTEPS) {
      short* bsb = (short*)(lds_raw + nb * BUF_BYTES + 8192);
      gload_lds16(bsrc0 + (ks + 1) * BK, bsb + bld0);
      gload_lds16(bsrc1 + (ks + 1) * BK, bsb + bld1);
      gload_lds16(bsrc2 + (ks + 1) * BK, bsb + bld2);
      gload_lds16(bsrc3 + (ks + 1) * BK, bsb + bld3);
      #pragma unroll
      for (int j = 0; j < 4; ++j) {
        ssq = fmaf(rA0[j], rA0[j], ssq);
        ssq = fmaf(rA1[j], rA1[j], ssq);
      }
      short* asb = (short*)(lds_raw + nb * BUF_BYTES);
      *(bf16x8*)&asb[sA] = cvt8(rA0, rA1);
    }
    // ---- prefetch A tile ks+2 into the (now free) named regs
    if (ks + 2 < KSTEPS) {
      rA0 = *(const f32x4*)(aptr + (ks + 2) * BK);
      rA1 = *(const f32x4*)(aptr + (ks + 2) * BK + 4);
    }
    // ---- compute tile ks from buffer cb
    {
      const short* asb = (const short*)(lds_raw + cb * BUF_BYTES);
      const short* bsb = (const short*)(lds_raw + cb * BUF_BYTES + 8192);
      const int swz = (fr & 7) << 3;
      #pragma unroll
      for (int ksub = 0; ksub < 2; ++ksub) {
        const int kk = ksub * 32 + (lane >> 4) * 8;
        bf16x8 af0 = *(const bf16x8*)&asb[((wm * 32 + fr) * BK + kk) ^ swz];
        bf16x8 af1 = *(const bf16x8*)&asb[((wm * 32 + 16 + fr) * BK + kk) ^ swz];
        bf16x8 bf0 = *(const bf16x8*)&bsb[((wn * 64 + fr) * BK + kk) ^ swz];
        bf16x8 bf1 = *(const bf16x8*)&bsb[((wn * 64 + 16 + fr) * BK + kk) ^ swz];
        bf16x8 bf2 = *(const bf16x8*)&bsb[((wn * 64 + 32 + fr) * BK + kk) ^ swz];
        bf16x8 bf3 = *(const bf16x8*)&bsb[((wn * 64 + 48 + fr) * BK + kk) ^ swz];
        acc[0][0] = __builtin_amdgcn_mfma_f32_16x16x32_bf16(af0, bf0, acc[0][0], 0, 0, 0);
        acc[0][1] = __builtin_amdgcn_mfma_f32_16x16x32_bf16(af0, bf1, acc[0][1], 0, 0, 0);
        acc[0][2] = __builtin_amdgcn_mfma_f32_16x16x32_bf16(af0, bf2, acc[0][2], 0, 0, 0);
        acc[0][3] = __builtin_amdgcn_mfma_f32_16x16x32_bf16(af0, bf3, acc[0][3], 0, 0, 0);
        acc[1][0] = __builtin_amdgcn_mfma_f32_16x16x32_bf16(af1, bf0, acc[1][0], 0, 0, 0);
        acc[1][1] = __builtin_amdgcn_mfma_f32_16x16x32_bf16(af1, bf1, acc[1][1], 0, 0, 0);
        acc[1][2] = __builtin_amdgcn_mfma_f32_16x16x32_bf16(af1, bf2, acc[1][2], 0, 0, 0);
        acc[1][3] = __builtin_amdgcn_mfma_f32_16x16x32_bf16(af1, bf3, acc[1][3], 0, 0, 0);
      }
    }
    __syncthreads();   // the ONLY barrier: next buffer ready, cur reads retired
  }

  // ---- per-row inverse norm: reduce over the 8 segment-owner lanes
  ssq += __shfl_xor(ssq, 1, 64);
  ssq += __shfl_xor(ssq, 2, 64);
  ssq += __shfl_xor(ssq, 4, 64);
  float* invx = (float*)lds_raw;           // reuse As0 (all reads retired)
  if (aseg == 0) invx[ar] = 1.f / fmaxf(sqrtf(ssq), CLAMP_EPS);
  __syncthreads();

  // ---- epilogue: C/D layout col=lane&15, row=(lane>>4)*4+reg
  #pragma unroll
  for (int fm = 0; fm < 2; ++fm) {
    #pragma unroll
    for (int r = 0; r < 4; ++r) {
      const int rl = wm * 32 + fm * 16 + (lane >> 4) * 4 + r;
      const float inv = invx[rl];
      float* orow = out + (size_t)(row0 + rl) * KC + wn * 64 + fr;
      #pragma unroll
      for (int fn = 0; fn < 4; ++fn)
        orow[fn * 16] = fmaf(acc[fm][fn][r] * inv, 0.5f, 0.5f);
    }
  }
}

extern "C" void kernel_launch(void* const* d_in, const int* in_sizes, int n_in,
                              void* d_out, int out_size, void* d_ws, size_t ws_size,
                              hipStream_t stream) {
  const float* x = (const float*)d_in[0];
  const float* c = (const float*)d_in[1];
  float* out = (float*)d_out;
  short* cn = (short*)d_ws;              // 256*1024 bf16 = 512 KB

  const int nrows = in_sizes[0] / DD;    // 32768
  center_norm_kernel<<<KC, 64, 0, stream>>>(c, cn);
  cossim_gemm_kernel<<<nrows / BM, 512, 0, stream>>>(x, cn, out);
}